// Round 16
// baseline (1666.057 us; speedup 1.0000x reference)
//
#include <hip/hip_runtime.h>
#include <hip/hip_bf16.h>
#include <math.h>

// Problem constants (fixed by the reference)
constexpr int LAYERS = 6;
constexpr int HEADS  = 12;
constexpr int DK     = 64;
constexpr int DM     = 768;
constexpr int DH     = 3072;
constexpr int BATCH  = 8;
constexpr int SEQ    = 1024;
constexpr int MROWS  = BATCH * SEQ;       // 8192
// 1/sqrt(768) * log2(e): attention logits computed in exp2 domain
constexpr float QSCALE = 0.03608439182435161f * 1.4426950408889634f;

typedef __attribute__((ext_vector_type(4))) float f32x4;
typedef __attribute__((ext_vector_type(8))) short bf16x8;
typedef __attribute__((ext_vector_type(4))) unsigned short u16x4;

enum { EPI_QKV = 0, EPI_PROJ = 1, EPI_RELU = 2, EPI_FFN2 = 3 };

__device__ __forceinline__ void gload_lds16(const void* g, void* l) {
  __builtin_amdgcn_global_load_lds(
      (const __attribute__((address_space(1))) void*)g,
      (__attribute__((address_space(3))) void*)l, 16, 0, 0);
}

// ---------------------------------------------------------------------------
// Positional embedding add: xb = bf16(x + pe)
// ---------------------------------------------------------------------------
__global__ __launch_bounds__(256) void posembed_kernel(
    const float* __restrict__ x, __hip_bfloat16* __restrict__ xb) {
  int idx = blockIdx.x * 256 + threadIdx.x;        // < 8192*768
  int d  = idx % DM;
  int bt = idx / DM;
  int t  = bt & (SEQ - 1);
  float expo = (float)(d & ~1) * (1.0f / (float)DM);
  float inv  = powf(10000.0f, -expo);
  float ang  = (float)t * inv;
  float pe   = (d & 1) ? cosf(ang) : sinf(ang);
  xb[idx] = __float2bfloat16(x[idx] + pe);
}

// ---------------------------------------------------------------------------
// Transpose + f32->bf16 convert:  out[batch][c][r] = in[batch][r][c]
// ---------------------------------------------------------------------------
__global__ __launch_bounds__(256) void transpose_conv(
    const float* __restrict__ in, __hip_bfloat16* __restrict__ out,
    int R, int C, long obatch) {
  __shared__ float tile[32][33];
  int batch = blockIdx.z;
  in  += (long)batch * R * C;
  out += (long)batch * obatch;
  int c0 = blockIdx.x * 32, r0 = blockIdx.y * 32;
  int tx = threadIdx.x, ty = threadIdx.y;          // (32,8)
  for (int i = 0; i < 4; i++) {
    int r = r0 + ty + i * 8;
    tile[ty + i * 8][tx] = in[(long)r * C + c0 + tx];
  }
  __syncthreads();
  for (int i = 0; i < 4; i++) {
    int oc = ty + i * 8;
    out[(long)(c0 + oc) * R + r0 + tx] = __float2bfloat16(tile[tx][oc]);
  }
}

// ---------------------------------------------------------------------------
// Merged QKV weight transpose: wq/wk/wv[l][head][DM][DK] -> qkvt[3][DM][DM]
// ---------------------------------------------------------------------------
__global__ __launch_bounds__(256) void qkv_transpose(
    const float* __restrict__ wq, const float* __restrict__ wk,
    const float* __restrict__ wv, __hip_bfloat16* __restrict__ out) {
  __shared__ float tile[32][33];
  const int z = blockIdx.z;                 // 0..35
  const int which = z / 12, head = z % 12;
  const float* in = (which == 0 ? wq : which == 1 ? wk : wv)
                    + (size_t)head * DM * DK;
  __hip_bfloat16* o = out + (size_t)which * DM * DM + (size_t)head * DK * DM;
  int c0 = blockIdx.x * 32, r0 = blockIdx.y * 32;  // c over DK, r over DM
  int tx = threadIdx.x, ty = threadIdx.y;          // (32,8)
  for (int i = 0; i < 4; i++) {
    int r = r0 + ty + i * 8;
    tile[ty + i * 8][tx] = in[(long)r * DK + c0 + tx];
  }
  __syncthreads();
  for (int i = 0; i < 4; i++) {
    int oc = ty + i * 8;
    o[(long)(c0 + oc) * DM + r0 + tx] = __float2bfloat16(tile[tx][oc]);
  }
}

// ---------------------------------------------------------------------------
// V transpose (bf16): v[96][1024][64] -> vt[96][64][1024]
// ---------------------------------------------------------------------------
__global__ __launch_bounds__(256) void vtrans_kernel(
    const __hip_bfloat16* __restrict__ v, __hip_bfloat16* __restrict__ vt) {
  __shared__ unsigned short tile[64][66];
  const int head = blockIdx.y;
  const int t0 = blockIdx.x * 64;
  const unsigned short* src =
      (const unsigned short*)v + (size_t)head * SEQ * DK + (size_t)t0 * DK;
  unsigned short* dst = (unsigned short*)vt + (size_t)head * SEQ * DK + t0;
  const int tid = threadIdx.x;
#pragma unroll
  for (int it = 0; it < 4; ++it) {
    int j = tid + it * 256;          // 0..1023
    int r = j >> 4;                  // t-row 0..63
    int c4 = (j & 15) * 4;           // d 0..60
    u16x4 d4 = *(const u16x4*)&src[(size_t)r * DK + c4];
    tile[r][c4 + 0] = d4[0]; tile[r][c4 + 1] = d4[1];
    tile[r][c4 + 2] = d4[2]; tile[r][c4 + 3] = d4[3];
  }
  __syncthreads();
#pragma unroll
  for (int it = 0; it < 4; ++it) {
    int j = tid + it * 256;
    int d = j >> 4;                  // 0..63
    int t4 = (j & 15) * 4;           // t 0..60
    u16x4 o4;
    o4[0] = tile[t4 + 0][d]; o4[1] = tile[t4 + 1][d];
    o4[2] = tile[t4 + 2][d]; o4[3] = tile[t4 + 3][d];
    *(u16x4*)&dst[(size_t)d * SEQ + t4] = o4;
  }
}

// ---------------------------------------------------------------------------
// MFMA GEMM v4: C[M x N] = A[M x K] @ BT[N x K]^T  (bf16, f32 acc)
// 128xBN tile, BK=64, 4 waves, 2-phase double-buffered (verified sync).
// 1D grid + XCD-bijective swizzle, n-inner ordering.
// LDS: one 128-B row per M-row, source-side XOR chunk swizzle.
// ---------------------------------------------------------------------------
template <int EPI, int BN>
__global__ __launch_bounds__(256, 2) void gemm_bt(
    const __hip_bfloat16* __restrict__ A,
    const __hip_bfloat16* __restrict__ BT,
    int K, int nx,
    const float* __restrict__ bias,
    const __hip_bfloat16* __restrict__ res,
    void* __restrict__ outp) {
  __shared__ __align__(16) char As[2][16384];        // [buf][128 rows x 128B]
  __shared__ __align__(16) char Bs[2][BN * 128];     // [buf][BN rows x 128B]
  constexpr int NF = BN / 32;                        // n-frags per wave

  const int nwg = gridDim.x;            // % 8 == 0
  const int cpx = nwg >> 3;
  const int orig = blockIdx.x;
  const int lid = (orig & 7) * cpx + (orig >> 3);
  const int m0 = (lid / nx) * 128;
  const int n0 = (lid % nx) * BN;

  const int tid = threadIdx.x;
  const int lane = tid & 63;
  const int w = tid >> 6;
  const int wm = w >> 1, wn = w & 1;
  const int g = lane >> 4, r16 = lane & 15;
  const int r7 = r16 & 7;

  f32x4 acc[4][NF] = {};

  auto stage = [&](int kt, int d) {
    const int k0 = kt * 64;
#pragma unroll
    for (int i = 0; i < 4; i++) {
      int c = tid + 256 * i;
      int r = c >> 3, cc = (c & 7) ^ (r & 7);
      gload_lds16(&A[(size_t)(m0 + r) * K + k0 + cc * 8], &As[d][c * 16]);
    }
#pragma unroll
    for (int i = 0; i < BN / 32; i++) {
      int c = tid + 256 * i;
      int r = c >> 3, cc = (c & 7) ^ (r & 7);
      gload_lds16(&BT[(size_t)(n0 + r) * K + k0 + cc * 8], &Bs[d][c * 16]);
    }
  };

  const int NT = K >> 6;
  stage(0, 0);
  asm volatile("s_waitcnt vmcnt(0)" ::: "memory");
  __builtin_amdgcn_s_barrier();
  __builtin_amdgcn_sched_barrier(0);

  for (int kt = 0; kt < NT; ++kt) {
    const int cur = kt & 1;
    if (kt + 1 < NT) stage(kt + 1, cur ^ 1);   // prefetch, in flight over compute

#pragma unroll
    for (int kk = 0; kk < 2; ++kk) {
      bf16x8 af[4], bfr[NF];
#pragma unroll
      for (int m = 0; m < 4; m++) {
        int R = wm * 64 + m * 16 + r16;
        af[m] = *(const bf16x8*)&As[cur][R * 128 + (((kk * 4 + g) ^ r7) << 4)];
      }
#pragma unroll
      for (int n = 0; n < NF; n++) {
        int R = wn * (BN / 2) + n * 16 + r16;
        bfr[n] = *(const bf16x8*)&Bs[cur][R * 128 + (((kk * 4 + g) ^ r7) << 4)];
      }
      __builtin_amdgcn_s_setprio(1);
#pragma unroll
      for (int m = 0; m < 4; m++)
#pragma unroll
        for (int n = 0; n < NF; n++)
          acc[m][n] = __builtin_amdgcn_mfma_f32_16x16x32_bf16(
              af[m], bfr[n], acc[m][n], 0, 0, 0);
      __builtin_amdgcn_s_setprio(0);
    }

    asm volatile("s_waitcnt vmcnt(0)" ::: "memory");   // next tile landed
    __builtin_amdgcn_s_barrier();                      // all reads of cur done
    __builtin_amdgcn_sched_barrier(0);
  }

#pragma unroll
  for (int m = 0; m < 4; m++)
#pragma unroll
    for (int n = 0; n < NF; n++)
#pragma unroll
      for (int r = 0; r < 4; r++) {
        int row = m0 + wm * 64 + m * 16 + g * 4 + r;
        int col = n0 + wn * (BN / 2) + n * 16 + r16;
        float v = acc[m][n][r];
        if (EPI == EPI_QKV) {
          int which = (col >= 2 * DM) ? 2 : (col >= DM ? 1 : 0);
          int hc = col - which * DM;
          int h = hc >> 6, dk = hc & 63;
          int b = row >> 10, t = row & (SEQ - 1);
          if (which == 0) v *= QSCALE;
          ((__hip_bfloat16*)outp)[(((size_t)(which * BATCH + b) * HEADS + h) * SEQ + t) * DK + dk] =
              __float2bfloat16(v);
        } else if (EPI == EPI_PROJ || EPI == EPI_FFN2) {
          size_t idx = (size_t)row * DM + col;
          ((__hip_bfloat16*)outp)[idx] = __float2bfloat16(
              v + bias[col] + __bfloat162float(res[idx]));
        } else {  // EPI_RELU
          v += bias[col];
          ((__hip_bfloat16*)outp)[(size_t)row * DH + col] =
              __float2bfloat16(v > 0.f ? v : 0.f);
        }
      }
}

// ---------------------------------------------------------------------------
// Flash attention v7 (non-causal, mask all-true).  QBLK=128: two 64-row
// q-halves per block share each staged K/V tile -- barriers and staging
// per q-row halved vs v6.  Sync structure identical to validated v6:
// same-wave P write->read fenced by lgkmcnt(0)+sched_barrier; V/K buffer
// publishing owned by barrier B (vmcnt(0) + s_barrier).
// ---------------------------------------------------------------------------
__global__ __launch_bounds__(256, 4) void flash_kernel(
    const __hip_bfloat16* __restrict__ qkv,
    const __hip_bfloat16* __restrict__ vt,
    __hip_bfloat16* __restrict__ obuf) {
  __shared__ __align__(16) char KL[2][8192];     // [buf][64 s][128B row, src-swz]
  __shared__ __align__(16) char VL[2][8192];     // [buf][64 d][128B row, src-swz]
  __shared__ __align__(16) char PsL[4][2048];    // [wave][16 t][128B row, swz]

  const int bid = blockIdx.x;
  const int qb = bid / 96;                 // 0..7 (128-row q blocks)
  const int bh = bid % 96;
  const int h = bh % HEADS, b = bh / HEADS;

  const int tid = threadIdx.x, lane = tid & 63, w = tid >> 6;
  const int g = lane >> 4, r16 = lane & 15;
  const int r7 = r16 & 7;

  const size_t headoff = ((size_t)b * HEADS + h) * SEQ * DK;
  const size_t planes = (size_t)BATCH * HEADS * SEQ * DK;
  const __hip_bfloat16* Q  = qkv + headoff;
  const __hip_bfloat16* Kg = qkv + planes + headoff;   // [1024][64]
  const __hip_bfloat16* Vg = vt + headoff;             // [64][1024]

  bf16x8 qf[2][2];
#pragma unroll
  for (int qh = 0; qh < 2; ++qh) {
    int qrow = qb * 128 + qh * 64 + w * 16 + r16;
    qf[qh][0] = *(const bf16x8*)&Q[(size_t)qrow * DK + g * 8];
    qf[qh][1] = *(const bf16x8*)&Q[(size_t)qrow * DK + 32 + g * 8];
  }

  f32x4 o_acc[2][4] = {};
  float m_run[2] = {-3e38f, -3e38f};
  float lsum[2][4] = {};

  const int s0j = tid, s1j = tid + 256;
  const int s0r = s0j >> 3, s0c = (s0j & 7) ^ (s0r & 7);
  const int s1r = s1j >> 3, s1c = (s1j & 7) ^ (s1r & 7);

  auto stage = [&](int tt, int d) {
    const int ss = tt * 64;
    gload_lds16(&Kg[(size_t)(ss + s0r) * DK + s0c * 8], &KL[d][s0j * 16]);
    gload_lds16(&Kg[(size_t)(ss + s1r) * DK + s1c * 8], &KL[d][s1j * 16]);
    gload_lds16(&Vg[(size_t)s0r * SEQ + ss + s0c * 8], &VL[d][s0j * 16]);
    gload_lds16(&Vg[(size_t)s1r * SEQ + ss + s1c * 8], &VL[d][s1j * 16]);
  };

  stage(0, 0);
  __syncthreads();

  for (int t = 0; t < SEQ / 64; ++t) {
    const int cur = t & 1;
    if (t < SEQ / 64 - 1) stage(t + 1, cur ^ 1);

#pragma unroll
    for (int qh = 0; qh < 2; ++qh) {
      // (1) S = Q K^T from KL[cur]
      f32x4 s_acc[4] = {};
#pragma unroll
      for (int n = 0; n < 4; ++n) {
        const int R = n * 16 + r16;
        bf16x8 k0 = *(const bf16x8*)&KL[cur][R * 128 + ((g ^ r7) << 4)];
        s_acc[n] = __builtin_amdgcn_mfma_f32_16x16x32_bf16(qf[qh][0], k0, s_acc[n], 0, 0, 0);
        bf16x8 k1 = *(const bf16x8*)&KL[cur][R * 128 + (((4 + g) ^ r7) << 4)];
        s_acc[n] = __builtin_amdgcn_mfma_f32_16x16x32_bf16(qf[qh][1], k1, s_acc[n], 0, 0, 0);
      }

      // (2) group-max online softmax (exact: per-4-row-block constant)
      float mx = -3e38f;
#pragma unroll
      for (int n = 0; n < 4; ++n)
        mx = fmaxf(mx, fmaxf(fmaxf(s_acc[n][0], s_acc[n][1]),
                             fmaxf(s_acc[n][2], s_acc[n][3])));
#pragma unroll
      for (int off = 1; off < 16; off <<= 1) mx = fmaxf(mx, __shfl_xor(mx, off, 64));

      if (__any(mx > m_run[qh] + 8.f)) {   // defer-max
        float mnew = fmaxf(m_run[qh], mx);
        float alpha = exp2f(m_run[qh] - mnew);
        m_run[qh] = mnew;
#pragma unroll
        for (int r = 0; r < 4; ++r) lsum[qh][r] *= alpha;
#pragma unroll
        for (int n = 0; n < 4; ++n)
#pragma unroll
          for (int r = 0; r < 4; ++r) o_acc[qh][n][r] *= alpha;
      }

      // (3) P = exp2(S - m) -> per-wave swizzled LDS; per-lane sums
      char* Pw = &PsL[w][0];
#pragma unroll
      for (int n = 0; n < 4; ++n)
#pragma unroll
        for (int r = 0; r < 4; ++r) {
          float p = exp2f(s_acc[n][r] - m_run[qh]);
          lsum[qh][r] += p;
          int trow = g * 4 + r;
          int chunk = n * 2 + (r16 >> 3);
          *(unsigned short*)&Pw[trow * 128 + ((chunk * 16) ^ ((trow & 7) << 4)) + r7 * 2] =
              __bfloat16_as_ushort(__float2bfloat16(p));
        }

      // same-wave LDS write->read fence
      asm volatile("s_waitcnt lgkmcnt(0)" ::: "memory");
      __builtin_amdgcn_sched_barrier(0);

      // (4) O += P V
#pragma unroll
      for (int kk = 0; kk < 2; ++kk) {
        bf16x8 pf = *(const bf16x8*)&Pw[r16 * 128 + (((kk * 4 + g) * 16) ^ (r7 << 4))];
#pragma unroll
        for (int n = 0; n < 4; ++n) {
          bf16x8 vf = *(const bf16x8*)&VL[cur][(n * 16 + r16) * 128 +
                                              (((kk * 4 + g) ^ r7) << 4)];
          o_acc[qh][n] = __builtin_amdgcn_mfma_f32_16x16x32_bf16(pf, vf, o_acc[qh][n], 0, 0, 0);
        }
      }
      // fence before qh=1 overwrites Pw (same wave, in-order DS + pin)
      asm volatile("s_waitcnt lgkmcnt(0)" ::: "memory");
      __builtin_amdgcn_sched_barrier(0);
    }

    // barrier B: staged tile complete + all waves done with buf[cur]
    asm volatile("s_waitcnt vmcnt(0)" ::: "memory");
    __builtin_amdgcn_s_barrier();
    __builtin_amdgcn_sched_barrier(0);
  }

  // final row-sum reduce + normalize + store, per q-half
#pragma unroll
  for (int qh = 0; qh < 2; ++qh) {
#pragma unroll
    for (int r = 0; r < 4; ++r)
#pragma unroll
      for (int off = 1; off < 16; off <<= 1)
        lsum[qh][r] += __shfl_xor(lsum[qh][r], off, 64);
    float rinv[4];
#pragma unroll
    for (int r = 0; r < 4; ++r) rinv[r] = 1.0f / lsum[qh][r];

#pragma unroll
    for (int n = 0; n < 4; ++n)
#pragma unroll
      for (int r = 0; r < 4; ++r) {
        int t = qb * 128 + qh * 64 + w * 16 + g * 4 + r;
        int col = h * DK + n * 16 + r16;
        obuf[((size_t)b * SEQ + t) * DM + col] =
            __float2bfloat16(o_acc[qh][n][r] * rinv[r]);
      }
  }
}

// ---------------------------------------------------------------------------
// LayerNorm over rows of 768 (bf16 input): xb(bf16), optional xout(f32)
// ---------------------------------------------------------------------------
__global__ __launch_bounds__(256) void ln_kernel(
    const __hip_bfloat16* __restrict__ y, const float* __restrict__ gam,
    const float* __restrict__ bet, float* __restrict__ xout,
    __hip_bfloat16* __restrict__ xb) {
  int row = blockIdx.x;
  const __hip_bfloat16* yr = y + (size_t)row * DM;
  int tid = threadIdx.x;
  float v[3];
  float s1 = 0.f, s2 = 0.f;
#pragma unroll
  for (int i = 0; i < 3; i++) {
    v[i] = __bfloat162float(yr[tid + i * 256]);
    s1 += v[i];
    s2 += v[i] * v[i];
  }
#pragma unroll
  for (int off = 1; off < 64; off <<= 1) {
    s1 += __shfl_xor(s1, off, 64);
    s2 += __shfl_xor(s2, off, 64);
  }
  __shared__ float ps1[4], ps2[4];
  int w = tid >> 6;
  if ((tid & 63) == 0) { ps1[w] = s1; ps2[w] = s2; }
  __syncthreads();
  s1 = ps1[0] + ps1[1] + ps1[2] + ps1[3];
  s2 = ps2[0] + ps2[1] + ps2[2] + ps2[3];
  float mu = s1 * (1.f / DM);
  float var = s2 * (1.f / DM) - mu * mu;
  float rstd = rsqrtf(var + 1e-5f);
#pragma unroll
  for (int i = 0; i < 3; i++) {
    int d = tid + i * 256;
    float o = (v[i] - mu) * rstd * gam[d] + bet[d];
    if (xout) xout[(size_t)row * DM + d] = o;
    xb[(size_t)row * DM + d] = __float2bfloat16(o);
  }
}

// ---------------------------------------------------------------------------
extern "C" void kernel_launch(void* const* d_in, const int* in_sizes, int n_in,
                              void* d_out, int out_size, void* d_ws, size_t ws_size,
                              hipStream_t stream) {
  const float* x_in   = (const float*)d_in[0];
  // d_in[1] = mask (all true) -- unused
  const float* wq     = (const float*)d_in[2];
  const float* wk     = (const float*)d_in[3];
  const float* wv     = (const float*)d_in[4];
  const float* proj_w = (const float*)d_in[5];
  const float* proj_b = (const float*)d_in[6];
  const float* ln1_g  = (const float*)d_in[7];
  const float* ln1_b  = (const float*)d_in[8];
  const float* w1     = (const float*)d_in[9];
  const float* b1     = (const float*)d_in[10];
  const float* w2     = (const float*)d_in[11];
  const float* b2     = (const float*)d_in[12];
  const float* ln2_g  = (const float*)d_in[13];
  const float* ln2_b  = (const float*)d_in[14];

  size_t off = 0;
  auto alloc = [&](size_t bytes) {
    void* p = (char*)d_ws + off;
    off += (bytes + 255) & ~(size_t)255;
    return p;
  };
  __hip_bfloat16* xb    = (__hip_bfloat16*)alloc((size_t)MROWS * DM * 2);
  __hip_bfloat16* qkvb  = (__hip_bfloat16*)alloc((size_t)3 * MROWS * DM * 2);
  __hip_bfloat16* obuf  = (__hip_bfloat16*)alloc((size_t)MROWS * DM * 2);
  __hip_bfloat16* ybuf  = (__hip_bfloat16*)alloc((size_t)MROWS * DM * 2);
  __hip_bfloat16* hbuf  = (__hip_bfloat16*)alloc((size_t)MROWS * DH * 2);
  __hip_bfloat16* qkvt  = (__hip_bfloat16*)alloc((size_t)3 * DM * DM * 2);
  __hip_bfloat16* projt = (__hip_bfloat16*)alloc((size_t)DM * DM * 2);
  __hip_bfloat16* w1t   = (__hip_bfloat16*)alloc((size_t)DH * DM * 2);
  __hip_bfloat16* w2t   = (__hip_bfloat16*)alloc((size_t)DM * DH * 2);
  __hip_bfloat16* vtb   = hbuf;   // V^T aliases hbuf (read before FFN1 writes)

  posembed_kernel<<<MROWS * DM / 256, 256, 0, stream>>>(x_in, xb);

  for (int l = 0; l < LAYERS; l++) {
    qkv_transpose<<<dim3(2, 24, 36), dim3(32, 8), 0, stream>>>(
        wq + (size_t)l * HEADS * DM * DK, wk + (size_t)l * HEADS * DM * DK,
        wv + (size_t)l * HEADS * DM * DK, qkvt);
    transpose_conv<<<dim3(24, 24, 1), dim3(32, 8), 0, stream>>>(
        proj_w + (size_t)l * DM * DM, projt, DM, DM, 0);
    transpose_conv<<<dim3(96, 24, 1), dim3(32, 8), 0, stream>>>(
        w1 + (size_t)l * DM * DH, w1t, DM, DH, 0);
    transpose_conv<<<dim3(24, 96, 1), dim3(32, 8), 0, stream>>>(
        w2 + (size_t)l * DH * DM, w2t, DH, DM, 0);

    // QKV: [8192 x 2304], BN=128, grid 18*64 = 1152 (%8==0)
    gemm_bt<EPI_QKV, 128><<<dim3(18 * 64), 256, 0, stream>>>(
        xb, qkvt, DM, 18, nullptr, nullptr, qkvb);
    vtrans_kernel<<<dim3(16, 96), 256, 0, stream>>>(
        qkvb + (size_t)2 * MROWS * DM, vtb);
    flash_kernel<<<dim3((SEQ / 128) * HEADS * BATCH), 256, 0, stream>>>(
        qkvb, vtb, obuf);
    // proj: [8192 x 768], BN=64, grid 64*12 = 768; residual = xb (bf16)
    gemm_bt<EPI_PROJ, 64><<<dim3(64 * 12), 256, 0, stream>>>(
        obuf, projt, DM, 12, proj_b + (size_t)l * DM, xb, ybuf);
    ln_kernel<<<MROWS, 256, 0, stream>>>(
        ybuf, ln1_g + (size_t)l * DM, ln1_b + (size_t)l * DM, nullptr, xb);
    // FFN1: [8192 x 3072], BN=128, grid 24*64 = 1536
    gemm_bt<EPI_RELU, 128><<<dim3(24 * 64), 256, 0, stream>>>(
        xb, w1t, DM, 24, b1 + (size_t)l * DH, nullptr, hbuf);
    // FFN2: [8192 x 768] K=3072, BN=64, grid 768; residual = xb (LN1 out)
    gemm_bt<EPI_FFN2, 64><<<dim3(64 * 12), 256, 0, stream>>>(
        hbuf, w2t, DH, 12, b2 + (size_t)l * DM, xb, ybuf);
    float* xo = (l == LAYERS - 1) ? (float*)d_out : nullptr;
    ln_kernel<<<MROWS, 256, 0, stream>>>(
        ybuf, ln2_g + (size_t)l * DM, ln2_b + (size_t)l * DM, xo, xb);
  }
}

// Round 17
// 1586.804 us; speedup vs baseline: 1.0499x; 1.0499x over previous
//
#include <hip/hip_runtime.h>
#include <hip/hip_bf16.h>
#include <math.h>

// Problem constants (fixed by the reference)
constexpr int LAYERS = 6;
constexpr int HEADS  = 12;
constexpr int DK     = 64;
constexpr int DM     = 768;
constexpr int DH     = 3072;
constexpr int BATCH  = 8;
constexpr int SEQ    = 1024;
constexpr int MROWS  = BATCH * SEQ;       // 8192
// 1/sqrt(768) * log2(e): attention logits computed in exp2 domain
constexpr float QSCALE = 0.03608439182435161f * 1.4426950408889634f;

typedef __attribute__((ext_vector_type(4))) float f32x4;
typedef __attribute__((ext_vector_type(8))) short bf16x8;
typedef __attribute__((ext_vector_type(4))) unsigned short u16x4;

enum { EPI_QKV = 0, EPI_PROJ = 1, EPI_RELU = 2, EPI_FFN2 = 3 };

__device__ __forceinline__ void gload_lds16(const void* g, void* l) {
  __builtin_amdgcn_global_load_lds(
      (const __attribute__((address_space(1))) void*)g,
      (__attribute__((address_space(3))) void*)l, 16, 0, 0);
}

// ---------------------------------------------------------------------------
// Positional embedding add: xb = bf16(x + pe)
// ---------------------------------------------------------------------------
__global__ __launch_bounds__(256) void posembed_kernel(
    const float* __restrict__ x, __hip_bfloat16* __restrict__ xb) {
  int idx = blockIdx.x * 256 + threadIdx.x;        // < 8192*768
  int d  = idx % DM;
  int bt = idx / DM;
  int t  = bt & (SEQ - 1);
  float expo = (float)(d & ~1) * (1.0f / (float)DM);
  float inv  = powf(10000.0f, -expo);
  float ang  = (float)t * inv;
  float pe   = (d & 1) ? cosf(ang) : sinf(ang);
  xb[idx] = __float2bfloat16(x[idx] + pe);
}

// ---------------------------------------------------------------------------
// Transpose + f32->bf16 convert:  out[batch][c][r] = in[batch][r][c]
// ---------------------------------------------------------------------------
__global__ __launch_bounds__(256) void transpose_conv(
    const float* __restrict__ in, __hip_bfloat16* __restrict__ out,
    int R, int C, long obatch) {
  __shared__ float tile[32][33];
  int batch = blockIdx.z;
  in  += (long)batch * R * C;
  out += (long)batch * obatch;
  int c0 = blockIdx.x * 32, r0 = blockIdx.y * 32;
  int tx = threadIdx.x, ty = threadIdx.y;          // (32,8)
  for (int i = 0; i < 4; i++) {
    int r = r0 + ty + i * 8;
    tile[ty + i * 8][tx] = in[(long)r * C + c0 + tx];
  }
  __syncthreads();
  for (int i = 0; i < 4; i++) {
    int oc = ty + i * 8;
    out[(long)(c0 + oc) * R + r0 + tx] = __float2bfloat16(tile[tx][oc]);
  }
}

// ---------------------------------------------------------------------------
// Merged QKV weight transpose: wq/wk/wv[l][head][DM][DK] -> qkvt[3][DM][DM]
// ---------------------------------------------------------------------------
__global__ __launch_bounds__(256) void qkv_transpose(
    const float* __restrict__ wq, const float* __restrict__ wk,
    const float* __restrict__ wv, __hip_bfloat16* __restrict__ out) {
  __shared__ float tile[32][33];
  const int z = blockIdx.z;                 // 0..35
  const int which = z / 12, head = z % 12;
  const float* in = (which == 0 ? wq : which == 1 ? wk : wv)
                    + (size_t)head * DM * DK;
  __hip_bfloat16* o = out + (size_t)which * DM * DM + (size_t)head * DK * DM;
  int c0 = blockIdx.x * 32, r0 = blockIdx.y * 32;  // c over DK, r over DM
  int tx = threadIdx.x, ty = threadIdx.y;          // (32,8)
  for (int i = 0; i < 4; i++) {
    int r = r0 + ty + i * 8;
    tile[ty + i * 8][tx] = in[(long)r * DK + c0 + tx];
  }
  __syncthreads();
  for (int i = 0; i < 4; i++) {
    int oc = ty + i * 8;
    o[(long)(c0 + oc) * DM + r0 + tx] = __float2bfloat16(tile[tx][oc]);
  }
}

// ---------------------------------------------------------------------------
// V transpose (bf16): v[96][1024][64] -> vt[96][64][1024]
// ---------------------------------------------------------------------------
__global__ __launch_bounds__(256) void vtrans_kernel(
    const __hip_bfloat16* __restrict__ v, __hip_bfloat16* __restrict__ vt) {
  __shared__ unsigned short tile[64][66];
  const int head = blockIdx.y;
  const int t0 = blockIdx.x * 64;
  const unsigned short* src =
      (const unsigned short*)v + (size_t)head * SEQ * DK + (size_t)t0 * DK;
  unsigned short* dst = (unsigned short*)vt + (size_t)head * SEQ * DK + t0;
  const int tid = threadIdx.x;
#pragma unroll
  for (int it = 0; it < 4; ++it) {
    int j = tid + it * 256;          // 0..1023
    int r = j >> 4;                  // t-row 0..63
    int c4 = (j & 15) * 4;           // d 0..60
    u16x4 d4 = *(const u16x4*)&src[(size_t)r * DK + c4];
    tile[r][c4 + 0] = d4[0]; tile[r][c4 + 1] = d4[1];
    tile[r][c4 + 2] = d4[2]; tile[r][c4 + 3] = d4[3];
  }
  __syncthreads();
#pragma unroll
  for (int it = 0; it < 4; ++it) {
    int j = tid + it * 256;
    int d = j >> 4;                  // 0..63
    int t4 = (j & 15) * 4;           // t 0..60
    u16x4 o4;
    o4[0] = tile[t4 + 0][d]; o4[1] = tile[t4 + 1][d];
    o4[2] = tile[t4 + 2][d]; o4[3] = tile[t4 + 3][d];
    *(u16x4*)&dst[(size_t)d * SEQ + t4] = o4;
  }
}

// ---------------------------------------------------------------------------
// MFMA GEMM v4: C[M x N] = A[M x K] @ BT[N x K]^T  (bf16, f32 acc)
// 128xBN tile, BK=64, 4 waves, 2-phase double-buffered (verified sync).
// 1D grid + XCD-bijective swizzle, n-inner ordering.
// LDS: one 128-B row per M-row, source-side XOR chunk swizzle.
// ---------------------------------------------------------------------------
template <int EPI, int BN>
__global__ __launch_bounds__(256, 2) void gemm_bt(
    const __hip_bfloat16* __restrict__ A,
    const __hip_bfloat16* __restrict__ BT,
    int K, int nx,
    const float* __restrict__ bias,
    const __hip_bfloat16* __restrict__ res,
    void* __restrict__ outp) {
  __shared__ __align__(16) char As[2][16384];        // [buf][128 rows x 128B]
  __shared__ __align__(16) char Bs[2][BN * 128];     // [buf][BN rows x 128B]
  constexpr int NF = BN / 32;                        // n-frags per wave

  const int nwg = gridDim.x;            // % 8 == 0
  const int cpx = nwg >> 3;
  const int orig = blockIdx.x;
  const int lid = (orig & 7) * cpx + (orig >> 3);
  const int m0 = (lid / nx) * 128;
  const int n0 = (lid % nx) * BN;

  const int tid = threadIdx.x;
  const int lane = tid & 63;
  const int w = tid >> 6;
  const int wm = w >> 1, wn = w & 1;
  const int g = lane >> 4, r16 = lane & 15;
  const int r7 = r16 & 7;

  f32x4 acc[4][NF] = {};

  auto stage = [&](int kt, int d) {
    const int k0 = kt * 64;
#pragma unroll
    for (int i = 0; i < 4; i++) {
      int c = tid + 256 * i;
      int r = c >> 3, cc = (c & 7) ^ (r & 7);
      gload_lds16(&A[(size_t)(m0 + r) * K + k0 + cc * 8], &As[d][c * 16]);
    }
#pragma unroll
    for (int i = 0; i < BN / 32; i++) {
      int c = tid + 256 * i;
      int r = c >> 3, cc = (c & 7) ^ (r & 7);
      gload_lds16(&BT[(size_t)(n0 + r) * K + k0 + cc * 8], &Bs[d][c * 16]);
    }
  };

  const int NT = K >> 6;
  stage(0, 0);
  asm volatile("s_waitcnt vmcnt(0)" ::: "memory");
  __builtin_amdgcn_s_barrier();
  __builtin_amdgcn_sched_barrier(0);

  for (int kt = 0; kt < NT; ++kt) {
    const int cur = kt & 1;
    if (kt + 1 < NT) stage(kt + 1, cur ^ 1);   // prefetch, in flight over compute

#pragma unroll
    for (int kk = 0; kk < 2; ++kk) {
      bf16x8 af[4], bfr[NF];
#pragma unroll
      for (int m = 0; m < 4; m++) {
        int R = wm * 64 + m * 16 + r16;
        af[m] = *(const bf16x8*)&As[cur][R * 128 + (((kk * 4 + g) ^ r7) << 4)];
      }
#pragma unroll
      for (int n = 0; n < NF; n++) {
        int R = wn * (BN / 2) + n * 16 + r16;
        bfr[n] = *(const bf16x8*)&Bs[cur][R * 128 + (((kk * 4 + g) ^ r7) << 4)];
      }
      __builtin_amdgcn_s_setprio(1);
#pragma unroll
      for (int m = 0; m < 4; m++)
#pragma unroll
        for (int n = 0; n < NF; n++)
          acc[m][n] = __builtin_amdgcn_mfma_f32_16x16x32_bf16(
              af[m], bfr[n], acc[m][n], 0, 0, 0);
      __builtin_amdgcn_s_setprio(0);
    }

    asm volatile("s_waitcnt vmcnt(0)" ::: "memory");   // next tile landed
    __builtin_amdgcn_s_barrier();                      // all reads of cur done
    __builtin_amdgcn_sched_barrier(0);
  }

#pragma unroll
  for (int m = 0; m < 4; m++)
#pragma unroll
    for (int n = 0; n < NF; n++)
#pragma unroll
      for (int r = 0; r < 4; r++) {
        int row = m0 + wm * 64 + m * 16 + g * 4 + r;
        int col = n0 + wn * (BN / 2) + n * 16 + r16;
        float v = acc[m][n][r];
        if (EPI == EPI_QKV) {
          int which = (col >= 2 * DM) ? 2 : (col >= DM ? 1 : 0);
          int hc = col - which * DM;
          int h = hc >> 6, dk = hc & 63;
          int b = row >> 10, t = row & (SEQ - 1);
          if (which == 0) v *= QSCALE;
          ((__hip_bfloat16*)outp)[(((size_t)(which * BATCH + b) * HEADS + h) * SEQ + t) * DK + dk] =
              __float2bfloat16(v);
        } else if (EPI == EPI_PROJ || EPI == EPI_FFN2) {
          size_t idx = (size_t)row * DM + col;
          ((__hip_bfloat16*)outp)[idx] = __float2bfloat16(
              v + bias[col] + __bfloat162float(res[idx]));
        } else {  // EPI_RELU
          v += bias[col];
          ((__hip_bfloat16*)outp)[(size_t)row * DH + col] =
              __float2bfloat16(v > 0.f ? v : 0.f);
        }
      }
}

// ---------------------------------------------------------------------------
// Flash attention v6 (non-causal, mask all-true).  Validated structure.
// P is per-wave LDS: same-wave ds_write->ds_read needs only lgkmcnt(0).
// V publishing owned entirely by barrier B (vmcnt(0) + s_barrier).
// ---------------------------------------------------------------------------
__global__ __launch_bounds__(256, 4) void flash_kernel(
    const __hip_bfloat16* __restrict__ qkv,
    const __hip_bfloat16* __restrict__ vt,
    __hip_bfloat16* __restrict__ obuf) {
  __shared__ __align__(16) char KL[2][8192];     // [buf][64 s][128B row, src-swz]
  __shared__ __align__(16) char VL[2][8192];     // [buf][64 d][128B row, src-swz]
  __shared__ __align__(16) char PsL[4][2048];    // [wave][16 t][128B row, swz]

  const int bid = blockIdx.x;
  const int qb = bid / 96;
  const int bh = bid % 96;
  const int h = bh % HEADS, b = bh / HEADS;

  const int tid = threadIdx.x, lane = tid & 63, w = tid >> 6;
  const int g = lane >> 4, r16 = lane & 15;
  const int r7 = r16 & 7;

  const size_t headoff = ((size_t)b * HEADS + h) * SEQ * DK;
  const size_t planes = (size_t)BATCH * HEADS * SEQ * DK;
  const __hip_bfloat16* Q  = qkv + headoff;
  const __hip_bfloat16* Kg = qkv + planes + headoff;   // [1024][64]
  const __hip_bfloat16* Vg = vt + headoff;             // [64][1024]

  bf16x8 qf[2];
  {
    int qrow = qb * 64 + w * 16 + r16;
    qf[0] = *(const bf16x8*)&Q[(size_t)qrow * DK + g * 8];
    qf[1] = *(const bf16x8*)&Q[(size_t)qrow * DK + 32 + g * 8];
  }

  f32x4 o_acc[4] = {};
  float m_run = -3e38f;
  float lsum[4] = {0.f, 0.f, 0.f, 0.f};

  const int s0j = tid, s1j = tid + 256;
  const int s0r = s0j >> 3, s0c = (s0j & 7) ^ (s0r & 7);
  const int s1r = s1j >> 3, s1c = (s1j & 7) ^ (s1r & 7);

  auto stage = [&](int tt, int d) {
    const int ss = tt * 64;
    gload_lds16(&Kg[(size_t)(ss + s0r) * DK + s0c * 8], &KL[d][s0j * 16]);
    gload_lds16(&Kg[(size_t)(ss + s1r) * DK + s1c * 8], &KL[d][s1j * 16]);
    gload_lds16(&Vg[(size_t)s0r * SEQ + ss + s0c * 8], &VL[d][s0j * 16]);
    gload_lds16(&Vg[(size_t)s1r * SEQ + ss + s1c * 8], &VL[d][s1j * 16]);
  };

  stage(0, 0);
  __syncthreads();

  for (int t = 0; t < SEQ / 64; ++t) {
    const int cur = t & 1;
    if (t < SEQ / 64 - 1) stage(t + 1, cur ^ 1);

    // (1) S = Q K^T from KL[cur]  (logits already in log2 units via QSCALE)
    f32x4 s_acc[4] = {};
#pragma unroll
    for (int n = 0; n < 4; ++n) {
      const int R = n * 16 + r16;
      bf16x8 k0 = *(const bf16x8*)&KL[cur][R * 128 + ((g ^ r7) << 4)];
      s_acc[n] = __builtin_amdgcn_mfma_f32_16x16x32_bf16(qf[0], k0, s_acc[n], 0, 0, 0);
      bf16x8 k1 = *(const bf16x8*)&KL[cur][R * 128 + (((4 + g) ^ r7) << 4)];
      s_acc[n] = __builtin_amdgcn_mfma_f32_16x16x32_bf16(qf[1], k1, s_acc[n], 0, 0, 0);
    }

    // (2) group-max online softmax (exact: per-4-row-block constant)
    float mx = -3e38f;
#pragma unroll
    for (int n = 0; n < 4; ++n)
      mx = fmaxf(mx, fmaxf(fmaxf(s_acc[n][0], s_acc[n][1]),
                           fmaxf(s_acc[n][2], s_acc[n][3])));
#pragma unroll
    for (int off = 1; off < 16; off <<= 1) mx = fmaxf(mx, __shfl_xor(mx, off, 64));

    if (__any(mx > m_run + 8.f)) {     // defer-max: rescale only on real growth
      float mnew = fmaxf(m_run, mx);
      float alpha = exp2f(m_run - mnew);
      m_run = mnew;
#pragma unroll
      for (int r = 0; r < 4; ++r) lsum[r] *= alpha;
#pragma unroll
      for (int n = 0; n < 4; ++n)
#pragma unroll
        for (int r = 0; r < 4; ++r) o_acc[n][r] *= alpha;
    }

    // (3) P = exp2(S - m) -> per-wave swizzled LDS; accumulate per-lane sums
    char* Pw = &PsL[w][0];
#pragma unroll
    for (int n = 0; n < 4; ++n)
#pragma unroll
      for (int r = 0; r < 4; ++r) {
        float p = exp2f(s_acc[n][r] - m_run);
        lsum[r] += p;
        int trow = g * 4 + r;
        int chunk = n * 2 + (r16 >> 3);
        *(unsigned short*)&Pw[trow * 128 + ((chunk * 16) ^ ((trow & 7) << 4)) + r7 * 2] =
            __bfloat16_as_ushort(__float2bfloat16(p));
      }

    // P ordering: same-wave LDS write->read only needs lgkmcnt (no barrier)
    asm volatile("s_waitcnt lgkmcnt(0)" ::: "memory");
    __builtin_amdgcn_sched_barrier(0);

    // (4) O += P V
#pragma unroll
    for (int kk = 0; kk < 2; ++kk) {
      bf16x8 pf = *(const bf16x8*)&Pw[r16 * 128 + (((kk * 4 + g) * 16) ^ (r7 << 4))];
#pragma unroll
      for (int n = 0; n < 4; ++n) {
        bf16x8 vf = *(const bf16x8*)&VL[cur][(n * 16 + r16) * 128 +
                                            (((kk * 4 + g) ^ r7) << 4)];
        o_acc[n] = __builtin_amdgcn_mfma_f32_16x16x32_bf16(pf, vf, o_acc[n], 0, 0, 0);
      }
    }

    // barrier B: staged tile complete + all waves done with buf[cur]
    asm volatile("s_waitcnt vmcnt(0)" ::: "memory");
    __builtin_amdgcn_s_barrier();
    __builtin_amdgcn_sched_barrier(0);
  }

  // final row-sum reduce (once) + normalize
#pragma unroll
  for (int r = 0; r < 4; ++r)
#pragma unroll
    for (int off = 1; off < 16; off <<= 1) lsum[r] += __shfl_xor(lsum[r], off, 64);
  float rinv[4];
#pragma unroll
  for (int r = 0; r < 4; ++r) rinv[r] = 1.0f / lsum[r];

#pragma unroll
  for (int n = 0; n < 4; ++n)
#pragma unroll
    for (int r = 0; r < 4; ++r) {
      int t = qb * 64 + w * 16 + g * 4 + r;
      int col = h * DK + n * 16 + r16;
      obuf[((size_t)b * SEQ + t) * DM + col] =
          __float2bfloat16(o_acc[n][r] * rinv[r]);
    }
}

// ---------------------------------------------------------------------------
// LayerNorm over rows of 768 (bf16 input): xb(bf16), optional xout(f32)
// ---------------------------------------------------------------------------
__global__ __launch_bounds__(256) void ln_kernel(
    const __hip_bfloat16* __restrict__ y, const float* __restrict__ gam,
    const float* __restrict__ bet, float* __restrict__ xout,
    __hip_bfloat16* __restrict__ xb) {
  int row = blockIdx.x;
  const __hip_bfloat16* yr = y + (size_t)row * DM;
  int tid = threadIdx.x;
  float v[3];
  float s1 = 0.f, s2 = 0.f;
#pragma unroll
  for (int i = 0; i < 3; i++) {
    v[i] = __bfloat162float(yr[tid + i * 256]);
    s1 += v[i];
    s2 += v[i] * v[i];
  }
#pragma unroll
  for (int off = 1; off < 64; off <<= 1) {
    s1 += __shfl_xor(s1, off, 64);
    s2 += __shfl_xor(s2, off, 64);
  }
  __shared__ float ps1[4], ps2[4];
  int w = tid >> 6;
  if ((tid & 63) == 0) { ps1[w] = s1; ps2[w] = s2; }
  __syncthreads();
  s1 = ps1[0] + ps1[1] + ps1[2] + ps1[3];
  s2 = ps2[0] + ps2[1] + ps2[2] + ps2[3];
  float mu = s1 * (1.f / DM);
  float var = s2 * (1.f / DM) - mu * mu;
  float rstd = rsqrtf(var + 1e-5f);
#pragma unroll
  for (int i = 0; i < 3; i++) {
    int d = tid + i * 256;
    float o = (v[i] - mu) * rstd * gam[d] + bet[d];
    if (xout) xout[(size_t)row * DM + d] = o;
    xb[(size_t)row * DM + d] = __float2bfloat16(o);
  }
}

// ---------------------------------------------------------------------------
extern "C" void kernel_launch(void* const* d_in, const int* in_sizes, int n_in,
                              void* d_out, int out_size, void* d_ws, size_t ws_size,
                              hipStream_t stream) {
  const float* x_in   = (const float*)d_in[0];
  // d_in[1] = mask (all true) -- unused
  const float* wq     = (const float*)d_in[2];
  const float* wk     = (const float*)d_in[3];
  const float* wv     = (const float*)d_in[4];
  const float* proj_w = (const float*)d_in[5];
  const float* proj_b = (const float*)d_in[6];
  const float* ln1_g  = (const float*)d_in[7];
  const float* ln1_b  = (const float*)d_in[8];
  const float* w1     = (const float*)d_in[9];
  const float* b1     = (const float*)d_in[10];
  const float* w2     = (const float*)d_in[11];
  const float* b2     = (const float*)d_in[12];
  const float* ln2_g  = (const float*)d_in[13];
  const float* ln2_b  = (const float*)d_in[14];

  size_t off = 0;
  auto alloc = [&](size_t bytes) {
    void* p = (char*)d_ws + off;
    off += (bytes + 255) & ~(size_t)255;
    return p;
  };
  __hip_bfloat16* xb    = (__hip_bfloat16*)alloc((size_t)MROWS * DM * 2);
  __hip_bfloat16* qkvb  = (__hip_bfloat16*)alloc((size_t)3 * MROWS * DM * 2);
  __hip_bfloat16* obuf  = (__hip_bfloat16*)alloc((size_t)MROWS * DM * 2);
  __hip_bfloat16* ybuf  = (__hip_bfloat16*)alloc((size_t)MROWS * DM * 2);
  __hip_bfloat16* hbuf  = (__hip_bfloat16*)alloc((size_t)MROWS * DH * 2);
  __hip_bfloat16* qkvt  = (__hip_bfloat16*)alloc((size_t)3 * DM * DM * 2);
  __hip_bfloat16* projt = (__hip_bfloat16*)alloc((size_t)DM * DM * 2);
  __hip_bfloat16* w1t   = (__hip_bfloat16*)alloc((size_t)DH * DM * 2);
  __hip_bfloat16* w2t   = (__hip_bfloat16*)alloc((size_t)DM * DH * 2);
  __hip_bfloat16* vtb   = hbuf;   // V^T aliases hbuf (read before FFN1 writes)

  posembed_kernel<<<MROWS * DM / 256, 256, 0, stream>>>(x_in, xb);

  for (int l = 0; l < LAYERS; l++) {
    qkv_transpose<<<dim3(2, 24, 36), dim3(32, 8), 0, stream>>>(
        wq + (size_t)l * HEADS * DM * DK, wk + (size_t)l * HEADS * DM * DK,
        wv + (size_t)l * HEADS * DM * DK, qkvt);
    transpose_conv<<<dim3(24, 24, 1), dim3(32, 8), 0, stream>>>(
        proj_w + (size_t)l * DM * DM, projt, DM, DM, 0);
    transpose_conv<<<dim3(96, 24, 1), dim3(32, 8), 0, stream>>>(
        w1 + (size_t)l * DM * DH, w1t, DM, DH, 0);
    transpose_conv<<<dim3(24, 96, 1), dim3(32, 8), 0, stream>>>(
        w2 + (size_t)l * DH * DM, w2t, DH, DM, 0);

    // QKV: [8192 x 2304], BN=128, grid 18*64 = 1152 (%8==0)
    gemm_bt<EPI_QKV, 128><<<dim3(18 * 64), 256, 0, stream>>>(
        xb, qkvt, DM, 18, nullptr, nullptr, qkvb);
    vtrans_kernel<<<dim3(16, 96), 256, 0, stream>>>(
        qkvb + (size_t)2 * MROWS * DM, vtb);
    flash_kernel<<<dim3((SEQ / 64) * HEADS * BATCH), 256, 0, stream>>>(
        qkvb, vtb, obuf);
    // proj: [8192 x 768], BN=64, grid 64*12 = 768; residual = xb (bf16)
    gemm_bt<EPI_PROJ, 64><<<dim3(64 * 12), 256, 0, stream>>>(
        obuf, projt, DM, 12, proj_b + (size_t)l * DM, xb, ybuf);
    ln_kernel<<<MROWS, 256, 0, stream>>>(
        ybuf, ln1_g + (size_t)l * DM, ln1_b + (size_t)l * DM, nullptr, xb);
    // FFN1: [8192 x 3072], BN=128, grid 24*64 = 1536
    gemm_bt<EPI_RELU, 128><<<dim3(24 * 64), 256, 0, stream>>>(
        xb, w1t, DM, 24, b1 + (size_t)l * DH, nullptr, hbuf);
    // FFN2: [8192 x 768] K=3072, BN=64, grid 768; residual = xb (LN1 out)
    gemm_bt<EPI_FFN2, 64><<<dim3(64 * 12), 256, 0, stream>>>(
        hbuf, w2t, DH, 12, b2 + (size_t)l * DM, xb, ybuf);
    float* xo = (l == LAYERS - 1) ? (float*)d_out : nullptr;
    ln_kernel<<<MROWS, 256, 0, stream>>>(
        ybuf, ln2_g + (size_t)l * DM, ln2_b + (size_t)l * DM, xo, xb);
  }
}